// Round 2
// baseline (828.185 us; speedup 1.0000x reference)
//
#include <hip/hip_runtime.h>
#include <cstdint>

#define NB 32
#define NS 4096
#define NC 768
#define NH 12
#define ND 64

// ws layout (float offsets)
#define WK_OFF     0            // wk_eff [C][H]            9216
#define SBIAS_OFF  9216         // [H]                      12
#define QHP_OFF    9472         // qh partials [8][768]     6144
#define CTX_OFF    15872        // ctx [B][H*D]             24576
#define SCORES_OFF 40960        // scores/attn [B][H][S]    1572864
#define YPART_OFF  1613824      // y partials [B][8][H][C]  2359296
// total 3973120 floats = 15.9 MB

// ---------------- K1a: qh partials = probe . Wq (+bq) ----------------
__global__ __launch_bounds__(256) void k_qh_part(
    const float* __restrict__ probe, const float* __restrict__ Wq,
    const float* __restrict__ bq, float* __restrict__ ws) {
  int bid = blockIdx.x;                    // 24 blocks
  int cc = bid & 7;                        // c-chunk 0..7 (96 c each)
  int t = (bid >> 3) * 256 + threadIdx.x;  // 0..767  (= h*64+d)
  const float* wq = Wq + t;
  float acc = (cc == 0) ? bq[t] : 0.f;
  int c0 = cc * 96;
  #pragma unroll 4
  for (int c = c0; c < c0 + 96; ++c)
    acc = fmaf(probe[c], wq[(size_t)c * NC], acc);
  ws[QHP_OFF + cc * NC + t] = acc;
}

// ---------------- K1b: wk_eff[c][h] = scale * qh[h,:] . Wk[c,h,:] ----------------
__global__ __launch_bounds__(256) void k_wk_eff(
    const float* __restrict__ Wk, const float* __restrict__ bk,
    float* __restrict__ ws) {
  __shared__ float qh[NC];
  int tid = threadIdx.x;
  for (int i = tid; i < NC; i += 256) {
    float s = 0.f;
    #pragma unroll
    for (int k = 0; k < 8; ++k) s += ws[QHP_OFF + k * NC + i];
    qh[i] = s;
  }
  __syncthreads();
  int tg = blockIdx.x * 256 + tid;         // 0..9215, 36 blocks
  int c = tg / NH, h = tg - c * NH;
  const float* wkp = Wk + (size_t)c * NC + h * ND;
  const float* qp = qh + h * ND;
  float acc = 0.f;
  #pragma unroll
  for (int d = 0; d < ND; ++d) acc = fmaf(qp[d], wkp[d], acc);
  ws[WK_OFF + tg] = 0.125f * acc;          // scale = 1/sqrt(64)
  if (blockIdx.x == 0 && tid < NH) {
    float sb = 0.f;
    #pragma unroll
    for (int d = 0; d < ND; ++d) sb = fmaf(qh[tid * ND + d], bk[tid * ND + d], sb);
    ws[SBIAS_OFF + tid] = 0.125f * sb;
  }
}

// ---------------- K2: scores[b][h][s] = x-row . wk_eff[:,h] + sbias[h] ----------------
__global__ __launch_bounds__(256) void k_scores(
    const float* __restrict__ x, const float* __restrict__ wk,
    float* __restrict__ ws) {
  int row = blockIdx.x * 256 + threadIdx.x;   // b*S + s, 131072 rows
  const float4* xr = (const float4*)(x + (size_t)row * NC);
  float acc[NH];
  #pragma unroll
  for (int h = 0; h < NH; ++h) acc[h] = 0.f;
  for (int c4 = 0; c4 < NC / 4; ++c4) {
    float4 xv = xr[c4];
    const float* w = wk + c4 * 4 * NH;        // uniform address -> s_load
    #pragma unroll
    for (int h = 0; h < NH; ++h) acc[h] = fmaf(xv.x, w[h], acc[h]);
    #pragma unroll
    for (int h = 0; h < NH; ++h) acc[h] = fmaf(xv.y, w[NH + h], acc[h]);
    #pragma unroll
    for (int h = 0; h < NH; ++h) acc[h] = fmaf(xv.z, w[2 * NH + h], acc[h]);
    #pragma unroll
    for (int h = 0; h < NH; ++h) acc[h] = fmaf(xv.w, w[3 * NH + h], acc[h]);
  }
  int b = row >> 12, s = row & (NS - 1);
  float* sc = ws + SCORES_OFF + (size_t)b * NH * NS + s;
  #pragma unroll
  for (int h = 0; h < NH; ++h) sc[(size_t)h * NS] = acc[h] + ws[SBIAS_OFF + h];
}

// ---------------- K3: in-place softmax over S per (b,h) ----------------
__device__ __forceinline__ float wred_max(float v) {
  #pragma unroll
  for (int o = 32; o >= 1; o >>= 1) v = fmaxf(v, __shfl_xor(v, o, 64));
  return v;
}
__device__ __forceinline__ float wred_sum(float v) {
  #pragma unroll
  for (int o = 32; o >= 1; o >>= 1) v += __shfl_xor(v, o, 64);
  return v;
}

__global__ __launch_bounds__(256) void k_softmax(float* __restrict__ ws) {
  float* sc = ws + SCORES_OFF + (size_t)blockIdx.x * NS;  // block per (b,h)
  int tid = threadIdx.x;
  float v[16];
  float m = -1e30f;
  #pragma unroll
  for (int k = 0; k < 16; ++k) { v[k] = sc[tid + (k << 8)]; m = fmaxf(m, v[k]); }
  __shared__ float red[4], red2[4];
  m = wred_max(m);
  int wid = tid >> 6, lane = tid & 63;
  if (lane == 0) red[wid] = m;
  __syncthreads();
  m = fmaxf(fmaxf(red[0], red[1]), fmaxf(red[2], red[3]));
  float s = 0.f;
  #pragma unroll
  for (int k = 0; k < 16; ++k) { v[k] = __expf(v[k] - m); s += v[k]; }
  s = wred_sum(s);
  if (lane == 0) red2[wid] = s;
  __syncthreads();
  s = red2[0] + red2[1] + red2[2] + red2[3];
  float inv = 1.f / s;
  #pragma unroll
  for (int k = 0; k < 16; ++k) sc[tid + (k << 8)] = v[k] * inv;
}

// ---------------- K4: y_part[b][chunk][h][c] = sum_{s in chunk} attn*x ----------------
__global__ __launch_bounds__(256) void k_pool(
    const float* __restrict__ x, const float* __restrict__ attn,
    float* __restrict__ ws) {
  int bid = blockIdx.x;          // 768 = 32 b * 8 s-chunks * 3 c-tiles
  int ct = bid % 3;
  int scnk = (bid / 3) & 7;
  int b = bid / 24;
  int c = ct * 256 + threadIdx.x;
  const float* xb = x + (size_t)b * NS * NC + c;
  const float* ab = attn + (size_t)b * NH * NS;
  float acc[NH];
  #pragma unroll
  for (int h = 0; h < NH; ++h) acc[h] = 0.f;
  for (int s4 = scnk * 128; s4 < scnk * 128 + 128; ++s4) {
    float4 a[NH];                // uniform addresses -> s_load_dwordx4
    #pragma unroll
    for (int h = 0; h < NH; ++h)
      a[h] = *(const float4*)(ab + (size_t)h * NS + s4 * 4);
    #pragma unroll
    for (int j = 0; j < 4; ++j) {
      float xv = xb[(size_t)(s4 * 4 + j) * NC];
      #pragma unroll
      for (int h = 0; h < NH; ++h) {
        float av = (j == 0) ? a[h].x : (j == 1) ? a[h].y : (j == 2) ? a[h].z : a[h].w;
        acc[h] = fmaf(av, xv, acc[h]);
      }
    }
  }
  float* yp = ws + YPART_OFF + ((size_t)(b * 8 + scnk) * NH) * NC + c;
  #pragma unroll
  for (int h = 0; h < NH; ++h) yp[(size_t)h * NC] = acc[h];
}

// ---------------- K5: ctx[b][h][d] = y[b][h][:] . Wv[:,h,d] + bv ----------------
__global__ __launch_bounds__(64) void k_ctx(
    const float* __restrict__ Wv, const float* __restrict__ bv,
    float* __restrict__ ws) {
  int bh = blockIdx.x;           // 384 = b*12+h
  int b = bh / NH, h = bh - b * NH;
  int d = threadIdx.x;           // 64
  const float* yp = ws + YPART_OFF + ((size_t)(b * 8) * NH + h) * NC;
  const float* wv = Wv + h * ND + d;
  float acc = bv[h * ND + d];
  for (int c = 0; c < NC; ++c) {
    float y = 0.f;               // uniform -> scalar pipe
    #pragma unroll
    for (int k = 0; k < 8; ++k) y += yp[(size_t)k * NH * NC + c];
    acc = fmaf(y, wv[(size_t)c * NC], acc);
  }
  ws[CTX_OFF + b * NC + h * ND + d] = acc;
}

// ---------------- K6: out[b][c'] = ctx[b][:] . Wo[:,c'] + bo ----------------
__global__ __launch_bounds__(256) void k_out(
    const float* __restrict__ Wo, const float* __restrict__ bo,
    const float* __restrict__ ws, float* __restrict__ out) {
  __shared__ float ctx[8 * NC];          // 24.5 KB: 8 batches' ctx
  int bid = blockIdx.x;                  // 48 = 12 cp-tiles * 4 b-groups
  int tile = bid % 12, bg = bid / 12;
  int tid = threadIdx.x;
  for (int i = tid; i < 8 * NC; i += 256)
    ctx[i] = ws[CTX_OFF + bg * 8 * NC + i];
  __syncthreads();
  int cp = tile * 64 + (tid & 63);
  int bq = tid >> 6;                     // 0..3
  float acc0 = 0.f, acc1 = 0.f;
  const float* wo = Wo + cp;
  for (int t = 0; t < NC; ++t) {
    float w = wo[(size_t)t * NC];
    acc0 = fmaf(ctx[bq * NC + t], w, acc0);          // LDS broadcast
    acc1 = fmaf(ctx[(bq + 4) * NC + t], w, acc1);
  }
  int b0 = bg * 8 + bq;
  float bias = bo[cp];
  out[b0 * NC + cp] = acc0 + bias;
  out[(b0 + 4) * NC + cp] = acc1 + bias;
}

extern "C" void kernel_launch(void* const* d_in, const int* in_sizes, int n_in,
                              void* d_out, int out_size, void* d_ws, size_t ws_size,
                              hipStream_t stream) {
  const float* x     = (const float*)d_in[0];
  const float* probe = (const float*)d_in[1];
  const float* Wq    = (const float*)d_in[2];
  const float* bq    = (const float*)d_in[3];
  const float* Wk    = (const float*)d_in[4];
  const float* bk    = (const float*)d_in[5];
  const float* Wv    = (const float*)d_in[6];
  const float* bv    = (const float*)d_in[7];
  const float* Wo    = (const float*)d_in[8];
  const float* bo    = (const float*)d_in[9];
  float* out = (float*)d_out;
  float* ws  = (float*)d_ws;

  hipLaunchKernelGGL(k_qh_part, dim3(24),  dim3(256), 0, stream, probe, Wq, bq, ws);
  hipLaunchKernelGGL(k_wk_eff,  dim3(36),  dim3(256), 0, stream, Wk, bk, ws);
  hipLaunchKernelGGL(k_scores,  dim3(512), dim3(256), 0, stream, x, ws + WK_OFF, ws);
  hipLaunchKernelGGL(k_softmax, dim3(NB * NH), dim3(256), 0, stream, ws);
  hipLaunchKernelGGL(k_pool,    dim3(768), dim3(256), 0, stream, x, ws + SCORES_OFF, ws);
  hipLaunchKernelGGL(k_ctx,     dim3(NB * NH), dim3(64), 0, stream, Wv, bv, ws);
  hipLaunchKernelGGL(k_out,     dim3(48),  dim3(256), 0, stream, Wo, bo, ws, out);
}